// Round 15
// baseline (54.899 us; speedup 1.0000x reference)
//
#include <hip/hip_runtime.h>
#include <math.h>

#define DDIM 512
#define BT 128          // block tile; 4 waves, each owns a 64x64 quadrant
#define NT 32           // N / BT
#define NTILES (NT * (NT + 1) / 2)   // 528 (= 8 * 66, divisible by 8)
#define NSLP 8          // K supersices of 64 (DDIM/64)
#define NCH 64          // 64-wide column chunks for partials

typedef __attribute__((ext_vector_type(4))) float f32x4;

// ---------- OCP e4m3fn scalar convert (RNE) — proven in R11/R12 ----------
__device__ __forceinline__ unsigned char f2e4m3(float x) {
  unsigned ux = __builtin_bit_cast(unsigned, x);
  unsigned sign = (ux >> 24) & 0x80u;
  float a = fminf(fabsf(x), 448.f);
  unsigned ua = __builtin_bit_cast(unsigned, a);
  int E = (int)((ua >> 23) & 0xff);
  if (E == 0) return (unsigned char)sign;
  E -= 127;
  int t = E - 3; if (t < -9) t = -9;
  float c = __builtin_bit_cast(float, (unsigned)((t + 150) << 23));
  float r = (a + c) - c;
  if (r <= 0.f) return (unsigned char)sign;
  unsigned ur = __builtin_bit_cast(unsigned, r);
  int Er = (int)((ur >> 23) & 0xff) - 127;
  if (Er < -6) {
    unsigned man = (unsigned)(r * 512.f + 0.5f);
    return (unsigned char)(sign | man);
  }
  unsigned man = (ur >> 20) & 7u;
  return (unsigned char)(sign | ((unsigned)(Er + 7) << 3) | man);
}
__device__ __forceinline__ float e4m32f(unsigned char b) {
  int e = (b >> 3) & 0xf, m = b & 7;
  float v = (e == 0) ? (float)m * 0.001953125f
                     : (float)(8 + m) * __builtin_bit_cast(float, (unsigned)((e + 117) << 23));
  return (b & 0x80) ? -v : v;
}

// pair-interleaved fragment-major layout (fp8):
// chunk (rt, u) = rows rt*16..+15, k = u*64..+63 -> 1 KB contiguous.
// lane (g<<4)|cl holds row rt*16+cl: bytes [k=u*64+g*8..+7] ++ [k=u*64+32+g*8..+7]
// -> one dwordx4 per lane feeds the two K=32 MFMA slices 2u and 2u+1.
__device__ __forceinline__ size_t chunk_off(int rt, int u) {
  return ((size_t)(rt * NSLP + u)) << 10;   // bytes
}

// ---- kernel 1: normalize rows w and w+B to fp8 pair-frag layout, pos[w] ----
__global__ void k_prep(const float* __restrict__ zi, const float* __restrict__ zj,
                       const float* __restrict__ tempp,
                       unsigned char* __restrict__ zf, float* __restrict__ pos,
                       float* __restrict__ accum, int B) {
  if (blockIdx.x == 0 && threadIdx.x == 0) {
    accum[0] = 0.f; accum[1] = 0.f;
    *(unsigned*)(accum + 2) = 0u;
  }
  int wv = (blockIdx.x * blockDim.x + threadIdx.x) >> 6;
  int lane = threadIdx.x & 63;
  if (wv >= B) return;
  const float* a = zi + (size_t)wv * DDIM;
  const float* b = zj + (size_t)wv * DDIM;
  float4 a0 = *(const float4*)(a + lane * 8);
  float4 a1 = *(const float4*)(a + lane * 8 + 4);
  float4 b0 = *(const float4*)(b + lane * 8);
  float4 b1 = *(const float4*)(b + lane * 8 + 4);
  float av[8] = {a0.x, a0.y, a0.z, a0.w, a1.x, a1.y, a1.z, a1.w};
  float bv[8] = {b0.x, b0.y, b0.z, b0.w, b1.x, b1.y, b1.z, b1.w};
  float sa = 0.f, sb = 0.f;
#pragma unroll
  for (int i = 0; i < 8; ++i) { sa = fmaf(av[i], av[i], sa); sb = fmaf(bv[i], bv[i], sb); }
#pragma unroll
  for (int off = 32; off; off >>= 1) { sa += __shfl_xor(sa, off, 64); sb += __shfl_xor(sb, off, 64); }
  float ia = 1.f / fmaxf(sqrtf(sa), 1e-8f);
  float ib = 1.f / fmaxf(sqrtf(sb), 1e-8f);
  unsigned long long pa = 0ull, pb = 0ull;
  float fa[8], fb[8];
#pragma unroll
  for (int i = 0; i < 8; ++i) {
    unsigned char qa = f2e4m3(av[i] * ia); fa[i] = e4m32f(qa);
    unsigned char qb = f2e4m3(bv[i] * ib); fb[i] = e4m32f(qb);
    pa |= ((unsigned long long)qa) << (8 * i);
    pb |= ((unsigned long long)qb) << (8 * i);
  }
  // thread covers k = lane*8..+7: u = lane>>3, half h = (lane>>2)&1, g = lane&3
  const int u = lane >> 3, h = (lane >> 2) & 1, g = lane & 3;
  {
    int r = wv;
    *(unsigned long long*)(zf + chunk_off(r >> 4, u) + (((g << 4) | (r & 15)) * 16 + h * 8)) = pa;
    r = wv + B;
    *(unsigned long long*)(zf + chunk_off(r >> 4, u) + (((g << 4) | (r & 15)) * 16 + h * 8)) = pb;
  }
  float pd = 0.f;
#pragma unroll
  for (int i = 0; i < 8; ++i) pd = fmaf(fa[i], fb[i], pd);
#pragma unroll
  for (int off = 32; off; off >>= 1) pd += __shfl_xor(pd, off, 64);
  if (lane == 0) {
    float p = pd / tempp[0];
    pos[wv] = p; pos[wv + B] = p;
  }
}

// ---- kernel 2: 4 waves x 64x64 quadrants, fp8 MFMA, barrier-free ----------
__global__ __launch_bounds__(256) void k_main(
    const unsigned char* __restrict__ zf, const float* __restrict__ pos,
    const float* __restrict__ tempp, float* __restrict__ partS,
    float* __restrict__ partC, int B) {
  // XCD-aware bijective swizzle (528 = 8 * 66)
  int tri = (blockIdx.x & 7) * (NTILES / 8) + (blockIdx.x >> 3);
  int bi = 0;
  while (tri >= NT - bi) { tri -= NT - bi; ++bi; }
  const int bj = bi + tri;
  const int r0 = bi * BT, c0 = bj * BT;
  const bool diag = (bi == bj);
  const float invt = 1.0f / tempp[0];

  const int t = threadIdx.x;
  const int lane = t & 63;
  const int wave = t >> 6;
  const int wr = wave >> 1, wc = wave & 1;   // 2x2 wave grid, each 64x64
  const int cl = lane & 15, g = lane >> 4;

  const int art0 = (r0 >> 4) + wr * 4;       // wave's 4 A row-tiles
  const int brt0 = (c0 >> 4) + wc * 4;       // wave's 4 B col-tiles

  f32x4 acc[4][4];
#pragma unroll
  for (int m = 0; m < 4; ++m)
#pragma unroll
    for (int n = 0; n < 4; ++n) acc[m][n] = (f32x4){0.f, 0.f, 0.f, 0.f};

#pragma unroll 2
  for (int u = 0; u < NSLP; ++u) {           // 8 supersices, no LDS, no barriers
    ulonglong2 aV[4], bV[4];
#pragma unroll
    for (int m = 0; m < 4; ++m)
      aV[m] = *(const ulonglong2*)(zf + chunk_off(art0 + m, u) + lane * 16);
#pragma unroll
    for (int n = 0; n < 4; ++n)
      bV[n] = *(const ulonglong2*)(zf + chunk_off(brt0 + n, u) + lane * 16);
#pragma unroll
    for (int m = 0; m < 4; ++m)
#pragma unroll
      for (int n = 0; n < 4; ++n)
        acc[m][n] = __builtin_amdgcn_mfma_f32_16x16x32_fp8_fp8(
            (long long)aV[m].x, (long long)bV[n].x, acc[m][n], 0, 0, 0);
#pragma unroll
    for (int m = 0; m < 4; ++m)
#pragma unroll
      for (int n = 0; n < 4; ++n)
        acc[m][n] = __builtin_amdgcn_mfma_f32_16x16x32_fp8_fp8(
            (long long)aV[m].y, (long long)bV[n].y, acc[m][n], 0, 0, 0);
  }

  // ---- epilogue (R3-proven): row partials + col partials (off-diag) ----
  int growv[16], gpartr[16];
  float pvr[16];
#pragma unroll
  for (int m = 0; m < 4; ++m)
#pragma unroll
    for (int reg = 0; reg < 4; ++reg) {
      int idx = m * 4 + reg;
      int grow = r0 + wr * 64 + m * 16 + g * 4 + reg;
      growv[idx] = grow;
      gpartr[idx] = (grow < B) ? grow + B : grow - B;
      pvr[idx] = pos[grow];
    }
  int gcolv[4], gpartc[4];
  float pvc[4];
#pragma unroll
  for (int n = 0; n < 4; ++n) {
    int gcol = c0 + wc * 64 + n * 16 + cl;
    gcolv[n] = gcol;
    gpartc[n] = (gcol < B) ? gcol + B : gcol - B;
    pvc[n] = pos[gcol];
  }

  float ssr[16], ccr[16], ssc[4], ccc[4];
#pragma unroll
  for (int i = 0; i < 16; ++i) { ssr[i] = 0.f; ccr[i] = 0.f; }
#pragma unroll
  for (int n = 0; n < 4; ++n) { ssc[n] = 0.f; ccc[n] = 0.f; }

#pragma unroll
  for (int m = 0; m < 4; ++m)
#pragma unroll
    for (int n = 0; n < 4; ++n)
#pragma unroll
      for (int reg = 0; reg < 4; ++reg) {
        const int idx = m * 4 + reg;
        float val = acc[m][n][reg] * invt;
        float e = __expf(val);
        bool isd = diag && (gcolv[n] == growv[idx]);
        if (!isd) {
          ssr[idx] += e;
          ccr[idx] += (gcolv[n] != gpartr[idx] && val > pvr[idx]) ? 1.f : 0.f;
        }
        if (!diag) {
          ssc[n] += e;
          ccc[n] += (growv[idx] != gpartc[n] && val > pvc[n]) ? 1.f : 0.f;
        }
      }

  // row partials: reduce over cl (16 lanes), write chunk 2*bj + wc
  const int chR = bj * 2 + wc;
#pragma unroll
  for (int idx = 0; idx < 16; ++idx) {
    float s = ssr[idx], c = ccr[idx];
#pragma unroll
    for (int off = 1; off < 16; off <<= 1) {
      s += __shfl_xor(s, off, 64);
      c += __shfl_xor(c, off, 64);
    }
    if (cl == 0) {
      partS[(size_t)growv[idx] * NCH + chR] = s;
      partC[(size_t)growv[idx] * NCH + chR] = c;
    }
  }
  // col partials: reduce over g (xor 16,32), write chunk 2*bi + wr
  if (!diag) {
    const int chC = bi * 2 + wr;
#pragma unroll
    for (int n = 0; n < 4; ++n) {
      float s = ssc[n], c = ccc[n];
      s += __shfl_xor(s, 16, 64); c += __shfl_xor(c, 16, 64);
      s += __shfl_xor(s, 32, 64); c += __shfl_xor(c, 32, 64);
      if (g == 0) {
        partS[(size_t)gcolv[n] * NCH + chC] = s;
        partC[(size_t)gcolv[n] * NCH + chC] = c;
      }
    }
  }
}

// ---- kernel 3: fused row-combine + reduction, 64 blocks (R14-proven) -------
__global__ __launch_bounds__(256) void k_fin(
    const float* __restrict__ partS, const float* __restrict__ partC,
    const float* __restrict__ pos, float* __restrict__ accum,
    float* __restrict__ out, int N) {
  const int lane = threadIdx.x & 63;
  const int wave = threadIdx.x >> 6;
  float lsum = 0.f, csum = 0.f;
#pragma unroll 4
  for (int i = 0; i < 16; ++i) {
    int r = blockIdx.x * 64 + wave * 16 + i;
    float s = partS[(size_t)r * NCH + lane];
    float c = partC[(size_t)r * NCH + lane];
#pragma unroll
    for (int off = 32; off; off >>= 1) {
      s += __shfl_xor(s, off, 64);
      c += __shfl_xor(c, off, 64);
    }
    lsum += logf(s) - pos[r];
    csum += c;
  }
  __shared__ float ls[4], cs[4];
  if (lane == 0) { ls[wave] = lsum; cs[wave] = csum; }
  __syncthreads();
  if (threadIdx.x == 0) {
    atomicAdd(&accum[0], ls[0] + ls[1] + ls[2] + ls[3]);
    atomicAdd(&accum[1], cs[0] + cs[1] + cs[2] + cs[3]);
    __threadfence();
    unsigned old = atomicAdd((unsigned*)(accum + 2), 1u);
    if (old == (unsigned)(gridDim.x - 1)) {
      float lt = atomicAdd(&accum[0], 0.f);
      float ct = atomicAdd(&accum[1], 0.f);
      out[0] = lt / (float)N;
      out[1] = ct / (float)N;
    }
  }
}

extern "C" void kernel_launch(void* const* d_in, const int* in_sizes, int n_in,
                              void* d_out, int out_size, void* d_ws, size_t ws_size,
                              hipStream_t stream) {
  const float* zi = (const float*)d_in[0];
  const float* zj = (const float*)d_in[1];
  const float* temp = (const float*)d_in[2];
  float* out = (float*)d_out;

  const int B = in_sizes[0] / DDIM;   // 2048
  const int N = 2 * B;                // 4096

  unsigned char* zf = (unsigned char*)d_ws;             // N*DDIM fp8 = 2 MB
  float* fws = (float*)(zf + (size_t)N * DDIM);
  float* pos   = fws;                                    // N
  float* partS = pos + N;                                // N*NCH = 1 MB
  float* partC = partS + (size_t)N * NCH;                // N*NCH = 1 MB
  float* accum = partC + (size_t)N * NCH;                // [loss, cnt, counter]

  k_prep<<<(B * 64) / 256, 256, 0, stream>>>(zi, zj, temp, zf, pos, accum, B);
  k_main<<<NTILES, 256, 0, stream>>>(zf, pos, temp, partS, partC, B);
  k_fin<<<64, 256, 0, stream>>>(partS, partC, pos, accum, out, N);
}

// Round 16
// 41.855 us; speedup vs baseline: 1.3116x; 1.3116x over previous
//
#include <hip/hip_runtime.h>
#include <math.h>

#define DDIM 512
#define THREADS 128     // 2 waves per block in k_main
#define BT 64           // block tile (M and N)
#define NT 64           // N / BT tile grid dimension
#define NTILES (NT * (NT + 1) / 2)   // 2080 triangular tiles (divisible by 8)
#define NSL 16          // K slices of 32 (DDIM/32)
#define NCH 64          // 64-wide column chunks for partials

typedef __attribute__((ext_vector_type(8))) __bf16 bf16x8;
typedef __attribute__((ext_vector_type(4))) float f32x4;
typedef __attribute__((ext_vector_type(8))) unsigned short ushort8;

__device__ __forceinline__ float bf2f(unsigned short u) {
  union { unsigned int i; float f; } v; v.i = ((unsigned int)u) << 16; return v.f;
}
__device__ __forceinline__ unsigned short f2bf(float f) {
  unsigned int u = __builtin_bit_cast(unsigned int, f);
  return (unsigned short)((u + 0x7fffu + ((u >> 16) & 1u)) >> 16);
}

// fragment-major layout: frag (rt, s) = rows rt*16..+15, k = s*32..+31.
// within frag: lane (g<<4)|cl holds row rt*16+cl, k s*32+g*8..+7 (16 B).
// byte offset = ((rt*16 + s)*64 + lane) * 16  -> 1 KB contiguous per frag.
__device__ __forceinline__ size_t frag_off_us(int rt, int s, int lane) {
  return ((size_t)(rt * NSL + s) * 64 + lane) * 8;   // in ushorts
}

// ---- kernel 1: normalize rows w and w+B to bf16 frag layout, pos[w] --------
//      (also zeroes the global accumulators used by k_fin)
__global__ void k_prep(const float* __restrict__ zi, const float* __restrict__ zj,
                       const float* __restrict__ tempp,
                       unsigned short* __restrict__ zf, float* __restrict__ pos,
                       float* __restrict__ accum, int B) {
  if (blockIdx.x == 0 && threadIdx.x == 0) {
    accum[0] = 0.f;                           // loss sum
    accum[1] = 0.f;                           // count sum
    *(unsigned*)(accum + 2) = 0u;             // done-counter
  }
  int wv = (blockIdx.x * blockDim.x + threadIdx.x) >> 6;
  int lane = threadIdx.x & 63;
  if (wv >= B) return;
  const float* a = zi + (size_t)wv * DDIM;
  const float* b = zj + (size_t)wv * DDIM;
  float4 a0 = *(const float4*)(a + lane * 8);
  float4 a1 = *(const float4*)(a + lane * 8 + 4);
  float4 b0 = *(const float4*)(b + lane * 8);
  float4 b1 = *(const float4*)(b + lane * 8 + 4);
  float av[8] = {a0.x, a0.y, a0.z, a0.w, a1.x, a1.y, a1.z, a1.w};
  float bv[8] = {b0.x, b0.y, b0.z, b0.w, b1.x, b1.y, b1.z, b1.w};
  float sa = 0.f, sb = 0.f;
#pragma unroll
  for (int i = 0; i < 8; ++i) { sa = fmaf(av[i], av[i], sa); sb = fmaf(bv[i], bv[i], sb); }
#pragma unroll
  for (int off = 32; off; off >>= 1) { sa += __shfl_xor(sa, off, 64); sb += __shfl_xor(sb, off, 64); }
  float ia = 1.f / fmaxf(sqrtf(sa), 1e-8f);
  float ib = 1.f / fmaxf(sqrtf(sb), 1e-8f);
  ushort8 ua, ub;
  float fa[8], fb[8];
#pragma unroll
  for (int i = 0; i < 8; ++i) {
    unsigned short x = f2bf(av[i] * ia); ua[i] = x; fa[i] = bf2f(x);
    unsigned short y = f2bf(bv[i] * ib); ub[i] = y; fb[i] = bf2f(y);
  }
  // lane covers k = lane*8..+7  ->  slice s = lane>>2, sub g = lane&3
  const int s = lane >> 2, g = lane & 3;
  {
    int r = wv;                                  // row wv
    *(ushort8*)(zf + frag_off_us(r >> 4, s, (g << 4) | (r & 15))) = ua;
    r = wv + B;                                  // row wv+B
    *(ushort8*)(zf + frag_off_us(r >> 4, s, (g << 4) | (r & 15))) = ub;
  }
  float pd = 0.f;
#pragma unroll
  for (int i = 0; i < 8; ++i) pd = fmaf(fa[i], fb[i], pd);
#pragma unroll
  for (int off = 32; off; off >>= 1) pd += __shfl_xor(pd, off, 64);
  if (lane == 0) {
    float p = pd / tempp[0];
    pos[wv] = p; pos[wv + B] = p;
  }
}

// ---- kernel 2: barrier-free MFMA Gram tiles from fragment-major global -----
__global__ __launch_bounds__(THREADS) void k_main(
    const unsigned short* __restrict__ zf, const float* __restrict__ pos,
    const float* __restrict__ tempp, float* __restrict__ partS,
    float* __restrict__ partC, int B) {
  // XCD-aware bijective swizzle (2080 = 8 * 260)
  int tri = (blockIdx.x & 7) * (NTILES / 8) + (blockIdx.x >> 3);
  int bi = 0;
  while (tri >= NT - bi) { tri -= NT - bi; ++bi; }
  const int bj = bi + tri;
  const int r0 = bi * BT, c0 = bj * BT;
  const bool diag = (bi == bj);
  const float invt = 1.0f / tempp[0];

  const int t = threadIdx.x;
  const int lane = t & 63;
  const int wave = t >> 6;                   // wave owns rows r0+wave*32..+31
  const int cl = lane & 15, g = lane >> 4;

  const int art0 = (r0 >> 4) + wave * 2;     // wave's two A row-tiles
  const int brt0 = (c0 >> 4);                // block's four B col-tiles

  f32x4 acc[2][4];
#pragma unroll
  for (int m = 0; m < 2; ++m)
#pragma unroll
    for (int n = 0; n < 4; ++n) acc[m][n] = (f32x4){0.f, 0.f, 0.f, 0.f};

#pragma unroll 4
  for (int s = 0; s < NSL; ++s) {            // 16 k-slices, no LDS, no barriers
    bf16x8 aF[2], bF[4];
#pragma unroll
    for (int m = 0; m < 2; ++m)
      aF[m] = *(const bf16x8*)(zf + frag_off_us(art0 + m, s, lane));
#pragma unroll
    for (int n = 0; n < 4; ++n)
      bF[n] = *(const bf16x8*)(zf + frag_off_us(brt0 + n, s, lane));
#pragma unroll
    for (int m = 0; m < 2; ++m)
#pragma unroll
      for (int n = 0; n < 4; ++n)
        acc[m][n] = __builtin_amdgcn_mfma_f32_16x16x32_bf16(aF[m], bF[n], acc[m][n], 0, 0, 0);
  }

  // ---- epilogue: fused exp-sum / rank-count, both directions ----
  int growv[8], gpartr[8];
  float pvr[8];
#pragma unroll
  for (int m = 0; m < 2; ++m)
#pragma unroll
    for (int reg = 0; reg < 4; ++reg) {
      int idx = m * 4 + reg;
      int grow = r0 + wave * 32 + m * 16 + g * 4 + reg;
      growv[idx] = grow;
      gpartr[idx] = (grow < B) ? grow + B : grow - B;
      pvr[idx] = pos[grow];
    }
  int gcolv[4], gpartc[4];
  float pvc[4];
#pragma unroll
  for (int n = 0; n < 4; ++n) {
    int gcol = c0 + n * 16 + cl;
    gcolv[n] = gcol;
    gpartc[n] = (gcol < B) ? gcol + B : gcol - B;
    pvc[n] = pos[gcol];
  }

  float ssr[8], ccr[8], ssc[4], ccc[4];
#pragma unroll
  for (int i = 0; i < 8; ++i) { ssr[i] = 0.f; ccr[i] = 0.f; }
#pragma unroll
  for (int n = 0; n < 4; ++n) { ssc[n] = 0.f; ccc[n] = 0.f; }

#pragma unroll
  for (int m = 0; m < 2; ++m)
#pragma unroll
    for (int n = 0; n < 4; ++n)
#pragma unroll
      for (int reg = 0; reg < 4; ++reg) {
        const int idx = m * 4 + reg;
        float val = acc[m][n][reg] * invt;
        float e = __expf(val);
        bool isd = diag && (gcolv[n] == growv[idx]);
        if (!isd) {
          ssr[idx] += e;
          ccr[idx] += (gcolv[n] != gpartr[idx] && val > pvr[idx]) ? 1.f : 0.f;
        }
        if (!diag) {
          ssc[n] += e;
          ccc[n] += (growv[idx] != gpartc[n] && val > pvc[n]) ? 1.f : 0.f;
        }
      }

  // row partials: rows live wholly in-wave -> reduce over cl, write chunk bj
#pragma unroll
  for (int idx = 0; idx < 8; ++idx) {
    float s = ssr[idx], c = ccr[idx];
#pragma unroll
    for (int off = 1; off < 16; off <<= 1) {
      s += __shfl_xor(s, off, 64);
      c += __shfl_xor(c, off, 64);
    }
    if (cl == 0) {
      partS[(size_t)growv[idx] * NCH + bj] = s;
      partC[(size_t)growv[idx] * NCH + bj] = c;
    }
  }

  // col partials: reduce over g in-wave, cross-wave combine via tiny LDS
  __shared__ float cbuf[256];                 // [0..127] S, [128..255] C
  if (!diag) {
#pragma unroll
    for (int n = 0; n < 4; ++n) {
      ssc[n] += __shfl_xor(ssc[n], 16, 64); ccc[n] += __shfl_xor(ccc[n], 16, 64);
      ssc[n] += __shfl_xor(ssc[n], 32, 64); ccc[n] += __shfl_xor(ccc[n], 32, 64);
    }
    if (g == 0) {
#pragma unroll
      for (int n = 0; n < 4; ++n) {
        cbuf[wave * 64 + n * 16 + cl] = ssc[n];
        cbuf[128 + wave * 64 + n * 16 + cl] = ccc[n];
      }
    }
  }
  __syncthreads();
  if (!diag && t < 64) {
    float s = cbuf[t] + cbuf[64 + t];
    float c = cbuf[128 + t] + cbuf[192 + t];
    partS[(size_t)(c0 + t) * NCH + bi] = s;
    partC[(size_t)(c0 + t) * NCH + bi] = c;
  }
}

// ---- kernel 3: fused row-combine + reduction, 64 blocks (low atomic count) -
__global__ __launch_bounds__(256) void k_fin(
    const float* __restrict__ partS, const float* __restrict__ partC,
    const float* __restrict__ pos, float* __restrict__ accum,
    float* __restrict__ out, int N) {
  const int lane = threadIdx.x & 63;
  const int wave = threadIdx.x >> 6;
  float lsum = 0.f, csum = 0.f;
  // block handles 64 rows; wave handles 16 of them
#pragma unroll 4
  for (int i = 0; i < 16; ++i) {
    int r = blockIdx.x * 64 + wave * 16 + i;
    float s = partS[(size_t)r * NCH + lane];
    float c = partC[(size_t)r * NCH + lane];
#pragma unroll
    for (int off = 32; off; off >>= 1) {
      s += __shfl_xor(s, off, 64);
      c += __shfl_xor(c, off, 64);
    }
    lsum += logf(s) - pos[r];
    csum += c;
  }
  __shared__ float ls[4], cs[4];
  if (lane == 0) { ls[wave] = lsum; cs[wave] = csum; }
  __syncthreads();
  if (threadIdx.x == 0) {
    atomicAdd(&accum[0], ls[0] + ls[1] + ls[2] + ls[3]);
    atomicAdd(&accum[1], cs[0] + cs[1] + cs[2] + cs[3]);
    __threadfence();
    unsigned old = atomicAdd((unsigned*)(accum + 2), 1u);
    if (old == (unsigned)(gridDim.x - 1)) {
      // last block: read totals via atomic no-op add (coherent view)
      float lt = atomicAdd(&accum[0], 0.f);
      float ct = atomicAdd(&accum[1], 0.f);
      out[0] = lt / (float)N;
      out[1] = ct / (float)N;
    }
  }
}

extern "C" void kernel_launch(void* const* d_in, const int* in_sizes, int n_in,
                              void* d_out, int out_size, void* d_ws, size_t ws_size,
                              hipStream_t stream) {
  const float* zi = (const float*)d_in[0];
  const float* zj = (const float*)d_in[1];
  const float* temp = (const float*)d_in[2];
  float* out = (float*)d_out;

  const int B = in_sizes[0] / DDIM;   // 2048
  const int N = 2 * B;                // 4096

  unsigned short* zf = (unsigned short*)d_ws;           // N*DDIM bf16, frag-major
  float* fws = (float*)(zf + (size_t)N * DDIM);
  float* pos   = fws;                                    // N
  float* partS = pos + N;                                // N*NCH = 1 MB
  float* partC = partS + (size_t)N * NCH;                // N*NCH = 1 MB
  float* accum = partC + (size_t)N * NCH;                // [loss, cnt, counter]

  k_prep<<<(B * 64) / 256, 256, 0, stream>>>(zi, zj, temp, zf, pos, accum, B);
  k_main<<<NTILES, THREADS, 0, stream>>>(zf, pos, temp, partS, partC, B);
  k_fin<<<64, 256, 0, stream>>>(partS, partC, pos, accum, out, N);
}